// Round 9
// baseline (321.093 us; speedup 1.0000x reference)
//
#include <hip/hip_runtime.h>

#define BSZ 8
#define SEQ 16
#define DIMN 512
#define SP 4096
#define KVL 4112

#define SCALE 0.0625f   // (512/2)^-0.5

#define CH  32           // KV positions per fused_attn block
#define NCH 129          // ceil(4112 / 32)
#define CHP 36           // padded LDS row stride

// workspace layout (float offsets)
#define QBUF  0          // 65536
#define KNEW  65536      // 65536
#define VNEW  131072     // 65536
#define MLBUF 196608     // 2 * NCH * 128 = 33024  (m plane, then l plane)
#define APART 229632     // NCH * 65536 = 8454144
#define ATTEN 8683776    // 65536

#define MLSTRIDE 16512   // NCH * 128

// ---------------------------------------------------------------------------
// 16-value cross-lane tree reduction (ownership halving). Each lane enters
// with acc[16] = partial dots over its 8 k-elements; lanes 0..15 exit with
// the full dot for row s = bitrev4(lane). Verified in scores/proj kernels.
// ---------------------------------------------------------------------------
__device__ __forceinline__ float tree16(const float* acc, bool b1, bool b2, bool b4, bool b8)
{
  float r8[8];
#pragma unroll
  for (int u = 0; u < 8; ++u) {
    float keep = b1 ? acc[u + 8] : acc[u];
    float send = b1 ? acc[u] : acc[u + 8];
    r8[u] = keep + __shfl_xor(send, 1);
  }
  float r4[4];
#pragma unroll
  for (int u = 0; u < 4; ++u) {
    float keep = b2 ? r8[u + 4] : r8[u];
    float send = b2 ? r8[u] : r8[u + 4];
    r4[u] = keep + __shfl_xor(send, 2);
  }
  float r2[2];
#pragma unroll
  for (int u = 0; u < 2; ++u) {
    float keep = b4 ? r4[u + 2] : r4[u];
    float send = b4 ? r4[u] : r4[u + 2];
    r2[u] = keep + __shfl_xor(send, 4);
  }
  float keep = b8 ? r2[1] : r2[0];
  float send = b8 ? r2[0] : r2[1];
  float r1 = keep + __shfl_xor(send, 8);
  r1 += __shfl_xor(r1, 16);
  r1 += __shfl_xor(r1, 32);
  return r1;
}

// ---------------------------------------------------------------------------
// Kernel 1/4: projection, dot-product style (verified R5/R6).
// grid (8 b, ncols/32), block 256.  Wave w handles cols e0 + w + 4*i.
// ---------------------------------------------------------------------------
__global__ __launch_bounds__(256) void proj_dot(
    const float* __restrict__ X,
    const float* __restrict__ W0, const float* __restrict__ W1,
    const float* __restrict__ W2,
    float* __restrict__ D0, float* __restrict__ D1, float* __restrict__ D2)
{
  int b = blockIdx.x;
  int e0 = blockIdx.y * 32;
  int t = threadIdx.x, lane = t & 63, w = t >> 6;

  float4 xa[SEQ], xb[SEQ];
  const float* xbase = X + (size_t)b * SEQ * DIMN + lane * 8;
#pragma unroll
  for (int s = 0; s < SEQ; ++s) {
    xa[s] = *(const float4*)(xbase + s * DIMN);
    xb[s] = *(const float4*)(xbase + s * DIMN + 4);
  }

  bool b1 = (lane & 1), b2 = (lane & 2), b4 = (lane & 4), b8 = (lane & 8);
#pragma unroll 2
  for (int i = 0; i < 8; ++i) {
    int e = e0 + w + 4 * i;              // wave-uniform
    int m = e >> 9, col = e & 511;
    const float* W = (m == 0) ? W0 : (m == 1) ? W1 : W2;
    const float* wrow = W + (size_t)col * DIMN + lane * 8;
    float4 ka = *(const float4*)(wrow);
    float4 kb = *(const float4*)(wrow + 4);

    float acc[SEQ];
#pragma unroll
    for (int s = 0; s < SEQ; ++s) {
      acc[s] = xa[s].x * ka.x + xa[s].y * ka.y + xa[s].z * ka.z + xa[s].w * ka.w
             + xb[s].x * kb.x + xb[s].y * kb.y + xb[s].z * kb.z + xb[s].w * kb.w;
    }
    float r1 = tree16(acc, b1, b2, b4, b8);
    if (lane < 16) {
      int s = ((lane & 1) << 3) | ((lane & 2) << 1) | ((lane & 4) >> 1) | ((lane & 8) >> 3);
      float* D = (m == 0) ? D0 : (m == 1) ? D1 : D2;
      D[(size_t)(b * SEQ + s) * DIMN + col] = r1;
    }
  }
}

// ---------------------------------------------------------------------------
// Kernel 2/4: fused flash attention chunk.  grid (8, NCH), block 256 (4 waves).
// Verified R6 structure; CH=32 to double grid-level parallelism (latency
// hiding), CHP pad for conflict-free LDS column writes.
// Phase 1 = scores (one position per wave-step, stride 4).
// Phase 2 = per-chunk softmax stats (16 threads/row, 2 pos each).
// Phase 3 = PV partial, 2 V-cols per thread -> apart; {m,l} -> mlbuf.
// ---------------------------------------------------------------------------
__global__ __launch_bounds__(256) void fused_attn(
    const float* __restrict__ qbuf, const float* __restrict__ cache_k,
    const float* __restrict__ knew, const float* __restrict__ mask,
    const float* __restrict__ cache_v, const float* __restrict__ vnew,
    float* __restrict__ weight, float* __restrict__ apart,
    float* __restrict__ mlbuf)
{
  __shared__ float pl[SEQ][CHP];
  __shared__ float lm[SEQ], ll[SEQ];
  int b = blockIdx.x, c = blockIdx.y;
  int p0 = c * CH;
  int len = KVL - p0; if (len > CH) len = CH;
  int t = threadIdx.x, lane = t & 63, w = t >> 6;

  // ---- phase 1: scores (identical math to verified scores_kernel) ----
  {
    float4 qa[SEQ], qb[SEQ];
    const float* qbase = qbuf + (size_t)b * SEQ * DIMN + lane * 8;
#pragma unroll
    for (int s = 0; s < SEQ; ++s) {
      qa[s] = *(const float4*)(qbase + s * DIMN);
      qb[s] = *(const float4*)(qbase + s * DIMN + 4);
    }
    bool b1 = (lane & 1), b2 = (lane & 2), b4 = (lane & 4), b8 = (lane & 8);
    int niter = (len - w + 3) >> 2;   // positions p0 + w + 4*i
#pragma unroll 2
    for (int i = 0; i < niter; ++i) {
      int p = p0 + w + 4 * i;
      const float* krow = (p < SP)
          ? (cache_k + ((size_t)b * 8192 + p) * DIMN)
          : (knew + (size_t)(b * SEQ + (p - SP)) * DIMN);
      float4 ka = *(const float4*)(krow + lane * 8);
      float4 kb = *(const float4*)(krow + lane * 8 + 4);

      float acc[SEQ];
#pragma unroll
      for (int s = 0; s < SEQ; ++s) {
        acc[s] = qa[s].x * ka.x + qa[s].y * ka.y + qa[s].z * ka.z + qa[s].w * ka.w
               + qb[s].x * kb.x + qb[s].y * kb.y + qb[s].z * kb.z + qb[s].w * kb.w;
      }
      float r1 = tree16(acc, b1, b2, b4, b8);
      if (lane < 16) {
        int s = ((lane & 1) << 3) | ((lane & 2) << 1) | ((lane & 4) >> 1) | ((lane & 8) >> 3);
        float sc = r1 * SCALE;
        weight[(size_t)(b * SEQ + s) * KVL + p] = sc;
        pl[s][p - p0] = sc;
      }
    }
  }
  __syncthreads();

  // ---- phase 2: per-chunk softmax stats.  16 threads per row, 2 pos each.
  // Row r's threads are a contiguous 16-lane group within one wave.
  {
    int r = t >> 4, j0 = (t & 15) * 2;
    float v[2];
#pragma unroll
    for (int k = 0; k < 2; ++k) {
      int j = j0 + k;
      v[k] = (j < len) ? pl[r][j] + mask[r * KVL + p0 + j] : -1e30f;
    }
    float m = fmaxf(v[0], v[1]);
    m = fmaxf(m, __shfl_xor(m, 1));
    m = fmaxf(m, __shfl_xor(m, 2));
    m = fmaxf(m, __shfl_xor(m, 4));
    m = fmaxf(m, __shfl_xor(m, 8));
    float e[2], sum = 0.f;
#pragma unroll
    for (int k = 0; k < 2; ++k) { e[k] = __expf(v[k] - m); sum += e[k]; }
    sum += __shfl_xor(sum, 1);
    sum += __shfl_xor(sum, 2);
    sum += __shfl_xor(sum, 4);
    sum += __shfl_xor(sum, 8);
#pragma unroll
    for (int k = 0; k < 2; ++k) pl[r][j0 + k] = e[k];
    if ((t & 15) == 0) { lm[r] = m; ll[r] = sum; }
  }
  __syncthreads();

  // ---- phase 3: PV partial (verified attnv loop, 2 cols per thread) ----
  float acc0[SEQ], acc1[SEQ];
#pragma unroll
  for (int q = 0; q < SEQ; ++q) { acc0[q] = 0.f; acc1[q] = 0.f; }

  int nj4 = len >> 2;   // 8 or 4
  for (int j4 = 0; j4 < nj4; ++j4) {
    float4 pv[SEQ];
#pragma unroll
    for (int q = 0; q < SEQ; ++q) pv[q] = *(const float4*)&pl[q][j4 * 4];
#pragma unroll
    for (int jj = 0; jj < 4; ++jj) {
      int p = p0 + j4 * 4 + jj;
      const float* vrow = (p < SP)
          ? (cache_v + ((size_t)b * 8192 + p) * DIMN)
          : (vnew + (size_t)(b * SEQ + (p - SP)) * DIMN);
      float va = vrow[t], vb = vrow[t + 256];
#pragma unroll
      for (int q = 0; q < SEQ; ++q) {
        float pj = (jj == 0) ? pv[q].x : (jj == 1) ? pv[q].y : (jj == 2) ? pv[q].z : pv[q].w;
        acc0[q] += pj * va;
        acc1[q] += pj * vb;
      }
    }
  }
  float* outp = apart + (size_t)c * 65536 + (size_t)b * SEQ * DIMN;
#pragma unroll
  for (int q = 0; q < SEQ; ++q) {
    outp[q * DIMN + t] = acc0[q];
    outp[q * DIMN + t + 256] = acc1[q];
  }
  if (t < SEQ) {
    mlbuf[c * 128 + b * SEQ + t] = lm[t];
    mlbuf[MLSTRIDE + c * 128 + b * SEQ + t] = ll[t];
  }
}

// ---------------------------------------------------------------------------
// Kernel 3/4: flash recombination.  grid (256 = 128 rows x 2 halves), blk 256.
// out[row][col] = sum_c exp(m_c - M) * pv_c[row][col] / sum_c exp(m_c - M) l_c
// ---------------------------------------------------------------------------
__global__ __launch_bounds__(256) void flash_reduce(
    const float* __restrict__ apart, const float* __restrict__ mlbuf,
    float* __restrict__ atten)
{
  __shared__ float msh[NCH], lsh[NCH], wfac[NCH];
  int row = blockIdx.x >> 1, half = blockIdx.x & 1;
  int t = threadIdx.x;

  if (t < NCH) {
    msh[t] = mlbuf[t * 128 + row];
    lsh[t] = mlbuf[MLSTRIDE + t * 128 + row];
  }
  __syncthreads();

  float M = -1e30f;
  for (int c = 0; c < NCH; ++c) M = fmaxf(M, msh[c]);
  if (t < NCH) wfac[t] = __expf(msh[t] - M);
  __syncthreads();

  float L = 0.f;
  for (int c = 0; c < NCH; ++c) L += wfac[c] * lsh[c];
  float inv = 1.0f / L;

  int col = half * 256 + t;
  const float* src = apart + (size_t)row * DIMN + col;
  float s = 0.f;
  for (int c = 0; c < NCH; ++c) s += wfac[c] * src[(size_t)c * 65536];
  atten[(size_t)row * DIMN + col] = s * inv;
}

// ---------------------------------------------------------------------------
extern "C" void kernel_launch(void* const* d_in, const int* in_sizes, int n_in,
                              void* d_out, int out_size, void* d_ws, size_t ws_size,
                              hipStream_t stream) {
  const float* x       = (const float*)d_in[0];
  // d_in[1] = start_pos (fixed 4096, baked into constants)
  const float* mask    = (const float*)d_in[2];
  const float* Wq      = (const float*)d_in[3];
  const float* Wk      = (const float*)d_in[4];
  const float* Wv      = (const float*)d_in[5];
  const float* Wo      = (const float*)d_in[6];
  const float* cache_k = (const float*)d_in[7];
  const float* cache_v = (const float*)d_in[8];
  float* out    = (float*)d_out;           // [8,16,512]
  float* weight = out + 65536;             // [8,16,4112]
  float* ws     = (float*)d_ws;

  // q/k/v projections, full-K (1536 concat cols, 32 per block)
  proj_dot<<<dim3(8, 48), 256, 0, stream>>>(
      x, Wq, Wk, Wv, ws + QBUF, ws + KNEW, ws + VNEW);
  // fused scores + weight output + chunk softmax + PV partials
  fused_attn<<<dim3(8, NCH), 256, 0, stream>>>(
      ws + QBUF, cache_k, ws + KNEW, mask, cache_v, ws + VNEW,
      weight, ws + APART, ws + MLBUF);
  // recombine NCH chunk partials with softmax rescale
  flash_reduce<<<dim3(256), 256, 0, stream>>>(
      ws + APART, ws + MLBUF, ws + ATTEN);
  // output projection (512 cols, 32 per block; m==0 always)
  proj_dot<<<dim3(8, 16), 256, 0, stream>>>(
      ws + ATTEN, Wo, Wo, Wo, out, out, out);
}

// Round 11
// 302.254 us; speedup vs baseline: 1.0623x; 1.0623x over previous
//
#include <hip/hip_runtime.h>

#define BSZ 8
#define SEQ 16
#define DIMN 512
#define SP 4096
#define KVL 4112

#define SCALE 0.0625f   // (512/2)^-0.5

#define CH  64           // KV positions per fused_attn block (R6 best)
#define NCH 65           // ceil(4112 / 64)
#define CHP 68           // padded LDS row stride (16B-aligned, conflict-light)

// workspace layout (float offsets)
#define QBUF  0          // 65536
#define KNEW  65536      // 65536
#define VNEW  131072     // 65536
#define MLBUF 196608     // 2 * NCH * 128 = 16640  (m plane, then l plane)
#define APART 213248     // NCH * 65536 = 4259840
#define ATTEN 4473088    // 65536

#define MLSTRIDE 8320    // NCH * 128

// ---------------------------------------------------------------------------
// 16-value cross-lane tree reduction (ownership halving). Each lane enters
// with acc[16] = partial dots over its 8 k-elements; lanes 0..15 exit with
// the full dot for row s = bitrev4(lane). Verified in scores/proj kernels.
// ---------------------------------------------------------------------------
__device__ __forceinline__ float tree16(const float* acc, bool b1, bool b2, bool b4, bool b8)
{
  float r8[8];
#pragma unroll
  for (int u = 0; u < 8; ++u) {
    float keep = b1 ? acc[u + 8] : acc[u];
    float send = b1 ? acc[u] : acc[u + 8];
    r8[u] = keep + __shfl_xor(send, 1);
  }
  float r4[4];
#pragma unroll
  for (int u = 0; u < 4; ++u) {
    float keep = b2 ? r8[u + 4] : r8[u];
    float send = b2 ? r8[u] : r8[u + 4];
    r4[u] = keep + __shfl_xor(send, 2);
  }
  float r2[2];
#pragma unroll
  for (int u = 0; u < 2; ++u) {
    float keep = b4 ? r4[u + 2] : r4[u];
    float send = b4 ? r4[u] : r4[u + 2];
    r2[u] = keep + __shfl_xor(send, 4);
  }
  float keep = b8 ? r2[1] : r2[0];
  float send = b8 ? r2[0] : r2[1];
  float r1 = keep + __shfl_xor(send, 8);
  r1 += __shfl_xor(r1, 16);
  r1 += __shfl_xor(r1, 32);
  return r1;
}

// ---------------------------------------------------------------------------
// Kernel 1/4: projection, dot-product style (verified R5/R6).
// grid (8 b, ncols/32), block 256.  Wave w handles cols e0 + w + 4*i.
// ---------------------------------------------------------------------------
__global__ __launch_bounds__(256) void proj_dot(
    const float* __restrict__ X,
    const float* __restrict__ W0, const float* __restrict__ W1,
    const float* __restrict__ W2,
    float* __restrict__ D0, float* __restrict__ D1, float* __restrict__ D2)
{
  int b = blockIdx.x;
  int e0 = blockIdx.y * 32;
  int t = threadIdx.x, lane = t & 63, w = t >> 6;

  float4 xa[SEQ], xb[SEQ];
  const float* xbase = X + (size_t)b * SEQ * DIMN + lane * 8;
#pragma unroll
  for (int s = 0; s < SEQ; ++s) {
    xa[s] = *(const float4*)(xbase + s * DIMN);
    xb[s] = *(const float4*)(xbase + s * DIMN + 4);
  }

  bool b1 = (lane & 1), b2 = (lane & 2), b4 = (lane & 4), b8 = (lane & 8);
#pragma unroll 2
  for (int i = 0; i < 8; ++i) {
    int e = e0 + w + 4 * i;              // wave-uniform
    int m = e >> 9, col = e & 511;
    const float* W = (m == 0) ? W0 : (m == 1) ? W1 : W2;
    const float* wrow = W + (size_t)col * DIMN + lane * 8;
    float4 ka = *(const float4*)(wrow);
    float4 kb = *(const float4*)(wrow + 4);

    float acc[SEQ];
#pragma unroll
    for (int s = 0; s < SEQ; ++s) {
      acc[s] = xa[s].x * ka.x + xa[s].y * ka.y + xa[s].z * ka.z + xa[s].w * ka.w
             + xb[s].x * kb.x + xb[s].y * kb.y + xb[s].z * kb.z + xb[s].w * kb.w;
    }
    float r1 = tree16(acc, b1, b2, b4, b8);
    if (lane < 16) {
      int s = ((lane & 1) << 3) | ((lane & 2) << 1) | ((lane & 4) >> 1) | ((lane & 8) >> 3);
      float* D = (m == 0) ? D0 : (m == 1) ? D1 : D2;
      D[(size_t)(b * SEQ + s) * DIMN + col] = r1;
    }
  }
}

// ---------------------------------------------------------------------------
// Kernel 2/4: fused flash attention chunk.  grid (8, NCH), block 256 (4 waves).
// R6-verified structure.  __launch_bounds__(256, 1): license the register
// allocator to keep qa/qb (128 VGPR of Q) RESIDENT instead of re-loading
// them inside the position loop (R7-R9 showed VGPR_Count=84 -> Q sunk into
// loop -> ~18 loads/position latency chain).  Grid is ~2 blocks/CU anyway,
// so high VGPR costs no real occupancy.
// ---------------------------------------------------------------------------
__global__ __launch_bounds__(256, 1) void fused_attn(
    const float* __restrict__ qbuf, const float* __restrict__ cache_k,
    const float* __restrict__ knew, const float* __restrict__ mask,
    const float* __restrict__ cache_v, const float* __restrict__ vnew,
    float* __restrict__ weight, float* __restrict__ apart,
    float* __restrict__ mlbuf)
{
  __shared__ float pl[SEQ][CHP];
  __shared__ float lm[SEQ], ll[SEQ];
  int b = blockIdx.x, c = blockIdx.y;
  int p0 = c * CH;
  int len = KVL - p0; if (len > CH) len = CH;
  int t = threadIdx.x, lane = t & 63, w = t >> 6;

  // ---- phase 1: scores (identical math to verified scores_kernel) ----
  {
    float4 qa[SEQ], qb[SEQ];
    const float* qbase = qbuf + (size_t)b * SEQ * DIMN + lane * 8;
#pragma unroll
    for (int s = 0; s < SEQ; ++s) {
      qa[s] = *(const float4*)(qbase + s * DIMN);
      qb[s] = *(const float4*)(qbase + s * DIMN + 4);
    }
    bool b1 = (lane & 1), b2 = (lane & 2), b4 = (lane & 4), b8 = (lane & 8);
    int niter = (len - w + 3) >> 2;   // positions p0 + w + 4*i
#pragma unroll 2
    for (int i = 0; i < niter; ++i) {
      int p = p0 + w + 4 * i;
      const float* krow = (p < SP)
          ? (cache_k + ((size_t)b * 8192 + p) * DIMN)
          : (knew + (size_t)(b * SEQ + (p - SP)) * DIMN);
      float4 ka = *(const float4*)(krow + lane * 8);
      float4 kb = *(const float4*)(krow + lane * 8 + 4);

      float acc[SEQ];
#pragma unroll
      for (int s = 0; s < SEQ; ++s) {
        acc[s] = qa[s].x * ka.x + qa[s].y * ka.y + qa[s].z * ka.z + qa[s].w * ka.w
               + qb[s].x * kb.x + qb[s].y * kb.y + qb[s].z * kb.z + qb[s].w * kb.w;
      }
      float r1 = tree16(acc, b1, b2, b4, b8);
      if (lane < 16) {
        int s = ((lane & 1) << 3) | ((lane & 2) << 1) | ((lane & 4) >> 1) | ((lane & 8) >> 3);
        float sc = r1 * SCALE;
        weight[(size_t)(b * SEQ + s) * KVL + p] = sc;
        pl[s][p - p0] = sc;
      }
    }
  }
  __syncthreads();

  // ---- phase 2: per-chunk softmax stats.  16 threads per row, 4 pos each.
  // Row r's threads are a contiguous 16-lane group within one wave.
  {
    int r = t >> 4, j0 = (t & 15) * 4;
    float v[4];
#pragma unroll
    for (int k = 0; k < 4; ++k) {
      int j = j0 + k;
      v[k] = (j < len) ? pl[r][j] + mask[r * KVL + p0 + j] : -1e30f;
    }
    float m = fmaxf(fmaxf(v[0], v[1]), fmaxf(v[2], v[3]));
    m = fmaxf(m, __shfl_xor(m, 1));
    m = fmaxf(m, __shfl_xor(m, 2));
    m = fmaxf(m, __shfl_xor(m, 4));
    m = fmaxf(m, __shfl_xor(m, 8));
    float e[4], sum = 0.f;
#pragma unroll
    for (int k = 0; k < 4; ++k) { e[k] = __expf(v[k] - m); sum += e[k]; }
    sum += __shfl_xor(sum, 1);
    sum += __shfl_xor(sum, 2);
    sum += __shfl_xor(sum, 4);
    sum += __shfl_xor(sum, 8);
#pragma unroll
    for (int k = 0; k < 4; ++k) pl[r][j0 + k] = e[k];
    if ((t & 15) == 0) { lm[r] = m; ll[r] = sum; }
  }
  __syncthreads();

  // ---- phase 3: PV partial (verified attnv loop, 2 cols per thread) ----
  float acc0[SEQ], acc1[SEQ];
#pragma unroll
  for (int q = 0; q < SEQ; ++q) { acc0[q] = 0.f; acc1[q] = 0.f; }

  int nj4 = len >> 2;   // 16 or 4
  for (int j4 = 0; j4 < nj4; ++j4) {
    float4 pv[SEQ];
#pragma unroll
    for (int q = 0; q < SEQ; ++q) pv[q] = *(const float4*)&pl[q][j4 * 4];
#pragma unroll
    for (int jj = 0; jj < 4; ++jj) {
      int p = p0 + j4 * 4 + jj;
      const float* vrow = (p < SP)
          ? (cache_v + ((size_t)b * 8192 + p) * DIMN)
          : (vnew + (size_t)(b * SEQ + (p - SP)) * DIMN);
      float va = vrow[t], vb = vrow[t + 256];
#pragma unroll
      for (int q = 0; q < SEQ; ++q) {
        float pj = (jj == 0) ? pv[q].x : (jj == 1) ? pv[q].y : (jj == 2) ? pv[q].z : pv[q].w;
        acc0[q] += pj * va;
        acc1[q] += pj * vb;
      }
    }
  }
  float* outp = apart + (size_t)c * 65536 + (size_t)b * SEQ * DIMN;
#pragma unroll
  for (int q = 0; q < SEQ; ++q) {
    outp[q * DIMN + t] = acc0[q];
    outp[q * DIMN + t + 256] = acc1[q];
  }
  if (t < SEQ) {
    mlbuf[c * 128 + b * SEQ + t] = lm[t];
    mlbuf[MLSTRIDE + c * 128 + b * SEQ + t] = ll[t];
  }
}

// ---------------------------------------------------------------------------
// Kernel 3/4: flash recombination.  grid (256 = 128 rows x 2 halves), blk 256.
// out[row][col] = sum_c exp(m_c - M) * pv_c[row][col] / sum_c exp(m_c - M) l_c
// ---------------------------------------------------------------------------
__global__ __launch_bounds__(256) void flash_reduce(
    const float* __restrict__ apart, const float* __restrict__ mlbuf,
    float* __restrict__ atten)
{
  __shared__ float msh[NCH], lsh[NCH], wfac[NCH];
  int row = blockIdx.x >> 1, half = blockIdx.x & 1;
  int t = threadIdx.x;

  if (t < NCH) {
    msh[t] = mlbuf[t * 128 + row];
    lsh[t] = mlbuf[MLSTRIDE + t * 128 + row];
  }
  __syncthreads();

  float M = -1e30f;
  for (int c = 0; c < NCH; ++c) M = fmaxf(M, msh[c]);
  if (t < NCH) wfac[t] = __expf(msh[t] - M);
  __syncthreads();

  float L = 0.f;
  for (int c = 0; c < NCH; ++c) L += wfac[c] * lsh[c];
  float inv = 1.0f / L;

  int col = half * 256 + t;
  const float* src = apart + (size_t)row * DIMN + col;
  float s = 0.f;
  for (int c = 0; c < NCH; ++c) s += wfac[c] * src[(size_t)c * 65536];
  atten[(size_t)row * DIMN + col] = s * inv;
}

// ---------------------------------------------------------------------------
extern "C" void kernel_launch(void* const* d_in, const int* in_sizes, int n_in,
                              void* d_out, int out_size, void* d_ws, size_t ws_size,
                              hipStream_t stream) {
  const float* x       = (const float*)d_in[0];
  // d_in[1] = start_pos (fixed 4096, baked into constants)
  const float* mask    = (const float*)d_in[2];
  const float* Wq      = (const float*)d_in[3];
  const float* Wk      = (const float*)d_in[4];
  const float* Wv      = (const float*)d_in[5];
  const float* Wo      = (const float*)d_in[6];
  const float* cache_k = (const float*)d_in[7];
  const float* cache_v = (const float*)d_in[8];
  float* out    = (float*)d_out;           // [8,16,512]
  float* weight = out + 65536;             // [8,16,4112]
  float* ws     = (float*)d_ws;

  // q/k/v projections, full-K (1536 concat cols, 32 per block)
  proj_dot<<<dim3(8, 48), 256, 0, stream>>>(
      x, Wq, Wk, Wv, ws + QBUF, ws + KNEW, ws + VNEW);
  // fused scores + weight output + chunk softmax + PV partials
  fused_attn<<<dim3(8, NCH), 256, 0, stream>>>(
      ws + QBUF, cache_k, ws + KNEW, mask, cache_v, ws + VNEW,
      weight, ws + APART, ws + MLBUF);
  // recombine NCH chunk partials with softmax rescale
  flash_reduce<<<dim3(256), 256, 0, stream>>>(
      ws + APART, ws + MLBUF, ws + ATTEN);
  // output projection (512 cols, 32 per block; m==0 always)
  proj_dot<<<dim3(8, 16), 256, 0, stream>>>(
      ws + ATTEN, Wo, Wo, Wo, out, out, out);
}